// Round 6
// baseline (288.875 us; speedup 1.0000x reference)
//
#include <hip/hip_runtime.h>
#include <hip/hip_bf16.h>
#include <cstdint>
#include <cstddef>

#define BATCH  4
#define SEQ    2048
#define EMBED  1024
#define NHEADS 16
#define HDIM   64

typedef __attribute__((ext_vector_type(8))) short  short8;   // 8 x bf16 (4 VGPRs)
typedef __attribute__((ext_vector_type(4))) float  floatx4;  // MFMA C/D
typedef __attribute__((ext_vector_type(4))) unsigned int uintx4;

#define MASK_NEG (-1.0e30f)   // finite "minus infinity": no inf-inf NaN paths
#define LOG2E    1.44269504f

__device__ __forceinline__ float bf2f(ushort u) {
  union { uint32_t i; float f; } v; v.i = ((uint32_t)u) << 16; return v.f;
}
__device__ __forceinline__ ushort f2bf(float f) {
  union { float f; uint32_t i; } v; v.f = f;
  uint32_t u = v.i;
  return (ushort)((u + 0x7fffu + ((u >> 16) & 1u)) >> 16);   // RNE
}
// packed RNE f32x2 -> bf16x2 (v_cvt_pk_bf16_f32 on gfx950)
__device__ __forceinline__ uint32_t f2bf_pk(float a, float b) {
  union { __hip_bfloat162 h; uint32_t u; } v;
  v.h = __float22bfloat162_rn(make_float2(a, b));
  return v.u;
}
// raw v_exp_f32 (2^x): guaranteed single instruction, denorm-flush is fine
// (underflowed P terms contribute nothing).
__device__ __forceinline__ float fast_exp2(float x) {
  float r;
  asm("v_exp_f32 %0, %1" : "=v"(r) : "v"(x));
  return r;
}
__device__ __forceinline__ floatx4 max4(floatx4 a, floatx4 b) {
  floatx4 r;
  r[0] = fmaxf(a[0], b[0]); r[1] = fmaxf(a[1], b[1]);
  r[2] = fmaxf(a[2], b[2]); r[3] = fmaxf(a[3], b[3]);
  return r;
}
// async global->LDS 16B/lane; LDS dst must be wave-uniform base + lane*16
__device__ __forceinline__ void gll16(const ushort* g, ushort* l) {
  __builtin_amdgcn_global_load_lds(
      (const __attribute__((address_space(1))) void*)g,
      (__attribute__((address_space(3))) void*)l, 16, 0, 0);
}

// ---------------------------------------------------------------------------
// Dtype detection (flag=1 bf16-packed, 0 fp32). Verified working since round 3.
// ---------------------------------------------------------------------------
__global__ __launch_bounds__(256) void detect_dtype(
    const uint32_t* __restrict__ x, int* __restrict__ flag) {
  __shared__ int sh[256];
  int tid = threadIdx.x;
  int c = 0;
#pragma unroll
  for (int i = 0; i < 16; i++) {
    uint32_t w = x[tid * 16 + i];
    uint32_t lo = w & 0xFFFFu;
    int e = (int)((lo >> 7) & 0xFF);
    if (lo == 0u || (e >= 100 && e <= 140)) c++;
  }
  sh[tid] = c;
  __syncthreads();
  if (tid == 0) {
    int s = 0;
    for (int i = 0; i < 256; i++) s += sh[i];
    *flag = (s >= 3500) ? 1 : 0;
  }
}

// vectorized x conversion: 4 elems/thread/step
__global__ __launch_bounds__(256) void cvt_bf16_v4(
    const void* __restrict__ in, ushort* __restrict__ out,
    const int* __restrict__ flag, int n4) {
  bool isbf = (*flag != 0);
  int stride = gridDim.x * 256;
  for (int i = blockIdx.x * 256 + threadIdx.x; i < n4; i += stride) {
    if (isbf) {
      ((uint2*)out)[i] = ((const uint2*)in)[i];
    } else {
      float4 f = ((const float4*)in)[i];
      uint2 o;
      o.x = f2bf_pk(f.x, f.y);
      o.y = f2bf_pk(f.z, f.w);
      ((uint2*)out)[i] = o;
    }
  }
}

// both biases in one launch: i<3072 -> bqb, else bob
__global__ __launch_bounds__(256) void cvt_biases(
    const void* __restrict__ bq, const void* __restrict__ bo,
    ushort* __restrict__ bqb, ushort* __restrict__ bob,
    const int* __restrict__ flag) {
  bool isbf = (*flag != 0);
  int i = blockIdx.x * 256 + threadIdx.x;
  if (i < 3 * EMBED) {
    bqb[i] = isbf ? ((const ushort*)bq)[i] : f2bf(((const float*)bq)[i]);
  } else {
    int j = i - 3 * EMBED;
    bob[j] = isbf ? ((const ushort*)bo)[j] : f2bf(((const float*)bo)[j]);
  }
}

__global__ __launch_bounds__(256) void transpose_cvt(
    const void* __restrict__ in, ushort* __restrict__ out,
    const int* __restrict__ flag, int R, int C) {
  bool isbf = (*flag != 0);
  __shared__ ushort tile[32][33];
  int bx = blockIdx.x * 32;
  int by = blockIdx.y * 32;
  int tx = threadIdx.x & 31, ty = threadIdx.x >> 5;
#pragma unroll
  for (int i = 0; i < 32; i += 8) {
    size_t idx = (size_t)(by + ty + i) * C + bx + tx;
    tile[ty + i][tx] = isbf ? ((const ushort*)in)[idx] : f2bf(((const float*)in)[idx]);
  }
  __syncthreads();
#pragma unroll
  for (int i = 0; i < 32; i += 8)
    out[(size_t)(bx + ty + i) * R + by + tx] = tile[tx][ty + i];
}

// ---------------------------------------------------------------------------
// Batched transpose: V (BH, S, D) bf16 -> VT (BH, D, S) bf16.
// ---------------------------------------------------------------------------
__global__ __launch_bounds__(256) void transpose_v(
    const ushort* __restrict__ in, ushort* __restrict__ out) {
  __shared__ ushort tile[32][33];
  int bh = blockIdx.z;
  int s0 = blockIdx.x * 32;
  int d0 = blockIdx.y * 32;
  int tx = threadIdx.x & 31, ty = threadIdx.x >> 5;
  const ushort* ip = in + (size_t)bh * SEQ * HDIM;
  ushort* op = out + (size_t)bh * SEQ * HDIM;
#pragma unroll
  for (int i = 0; i < 32; i += 8)
    tile[ty + i][tx] = ip[(size_t)(s0 + ty + i) * HDIM + d0 + tx];
  __syncthreads();
#pragma unroll
  for (int i = 0; i < 32; i += 8)
    op[(size_t)(d0 + ty + i) * SEQ + s0 + tx] = tile[tx][ty + i];
}

// ---------------------------------------------------------------------------
// GEMM v2: plain block mapping, BK=64, global_load_lds width-16 staging into
// XOR-chunk-swizzled unpadded LDS. Unchanged from round 4.
// ---------------------------------------------------------------------------
template <int EPI>
__global__ __launch_bounds__(256) void gemm128(
    const ushort* __restrict__ A, const ushort* __restrict__ BT,
    const ushort* __restrict__ bias,
    ushort* __restrict__ out0, ushort* __restrict__ out1, ushort* __restrict__ out2,
    const int* __restrict__ flag,
    int M, int N, int K) {
  __shared__ __align__(16) ushort Al[128 * 64];
  __shared__ __align__(16) ushort Bl[128 * 64];

  const int tid  = threadIdx.x;
  const int lane = tid & 63, wave = tid >> 6;
  const int quad = lane >> 4, l15 = lane & 15;
  const int wm = wave >> 1, wn = wave & 1;
  const int rowA0 = blockIdx.y * 128;
  const int colB0 = blockIdx.x * 128;

  floatx4 acc[4][4] = {};

  int srow[4], sc8[4];
#pragma unroll
  for (int j = 0; j < 4; j++) {
    int s = tid + j * 256;
    srow[j] = s >> 3;
    sc8[j] = ((s & 7) ^ (srow[j] & 7)) * 8;
  }

  for (int kk = 0; kk < K; kk += 64) {
    __syncthreads();
#pragma unroll
    for (int j = 0; j < 4; j++)
      gll16(&A[(size_t)(rowA0 + srow[j]) * K + kk + sc8[j]], &Al[(tid + j * 256) * 8]);
#pragma unroll
    for (int j = 0; j < 4; j++)
      gll16(&BT[(size_t)(colB0 + srow[j]) * K + kk + sc8[j]], &Bl[(tid + j * 256) * 8]);
    __syncthreads();

#pragma unroll
    for (int h = 0; h < 2; h++) {
      short8 af[4], bf[4];
#pragma unroll
      for (int mt = 0; mt < 4; mt++) {
        int row = wm * 64 + mt * 16 + l15;
        int pos = (quad + 4 * h) ^ (l15 & 7);
        af[mt] = *(const short8*)&Al[row * 64 + pos * 8];
      }
#pragma unroll
      for (int nt = 0; nt < 4; nt++) {
        int row = wn * 64 + nt * 16 + l15;
        int pos = (quad + 4 * h) ^ (l15 & 7);
        bf[nt] = *(const short8*)&Bl[row * 64 + pos * 8];
      }
#pragma unroll
      for (int mt = 0; mt < 4; mt++)
#pragma unroll
        for (int nt = 0; nt < 4; nt++)
          acc[mt][nt] = __builtin_amdgcn_mfma_f32_16x16x32_bf16(af[mt], bf[nt], acc[mt][nt], 0, 0, 0);
    }
  }

  const bool isbf = (EPI == 1) ? (*flag != 0) : true;

#pragma unroll
  for (int mt = 0; mt < 4; mt++)
#pragma unroll
    for (int nt = 0; nt < 4; nt++)
#pragma unroll
      for (int r = 0; r < 4; r++) {
        int row = rowA0 + wm * 64 + mt * 16 + quad * 4 + r;
        int col = colB0 + wn * 64 + nt * 16 + l15;
        float v = acc[mt][nt][r] + bf2f(bias[col]);
        if (EPI == 0) {
          int three = col >> 10, rem = col & 1023, h = rem >> 6, d = rem & 63;
          int b = row >> 11, s = row & 2047;
          ushort* dst = (three == 0) ? out0 : (three == 1) ? out1 : out2;
          dst[((size_t)(b * NHEADS + h) * SEQ + s) * HDIM + d] = f2bf(v);
        } else {
          if (isbf) out0[(size_t)row * N + col] = f2bf(v);
          else      ((float*)out0)[(size_t)row * N + col] = v;
        }
      }
}

// ---------------------------------------------------------------------------
// Flash attention v13: r4 envelope (64-row q-tiles, 16 rows/wave, diagonal
// pairing, grid 1024 = 4 blk/CU = 16 waves/CU, DMA staging) + key-permuted
// QK^T layout that makes P lane-local for PV -> Pl LDS buffer DELETED.
//   Fragment kct loads K rows kappa(kct,m) = (kct&1)*32 + (m>>2)*8 +
//   (kct>>1)*4 + (m&3); the MFMA C-layout then leaves lane (quad,l15)
//   holding scores for keys (kct&1)*32 + quad*8 + (kct>>1)*4 + r — exactly
//   the PV A-operand key set. exps are cvt_pk'd straight into A-fragment
//   words (pa0/pa1). DS per wave-tile 240 -> 192 cyc; LDS 40960 -> 32768.
//   Storage swizzle changed to f(row) = (row&3)|(((row>>3)&1)<<2) (read rows
//   of the permuted pattern have row&7 in {0..3} only; old f would collapse
//   to 4 chunk columns = 16-way conflicts). Verified per-instruction: K-reads
//   and V-reads spread 8 lanes/chunk-column (conflict-free; 2-way row
//   aliasing only, which is free per m136). ALiBi/mask constants re-derived
//   for permuted keys (quad*8 term -> fold into qrel).
// Rest unchanged from r4: defer-max THR=8, fast_exp2, quad-partial li,
// peeled masked diagonal, 1 barrier/iter, XCD bh-grouping.
// ---------------------------------------------------------------------------
__global__ __launch_bounds__(256, 4) void attn_kernel(
    const ushort* __restrict__ Q, const ushort* __restrict__ K,
    const ushort* __restrict__ VT, ushort* __restrict__ Oout) {
  __shared__ __align__(16) ushort Kl[2][64 * 64];   // [key][d], f-swizzled
  __shared__ __align__(16) ushort Vt[2][64 * 64];   // [d][key], f-swizzled

  const int tid  = threadIdx.x;
  const int lane = tid & 63, wave = tid >> 6;
  const int quad = lane >> 4, l15 = lane & 15;

  // XCD-aware remap: blocks L with L%8==xcd form one XCD's resident set;
  // give each xcd 8 whole (b,h) groups so K/V (8 x 512KB) fits its L2.
  const int L   = blockIdx.x + 16 * blockIdx.y + 256 * blockIdx.z;  // 0..1023
  const int xcd = L & 7;
  const int idx = L >> 3;                 // 0..127
  const int bh  = xcd * 8 + (idx >> 4);   // 0..63
  const int p   = idx & 15;               // diagonal pair index
  const int h   = bh & 15, b = bh >> 4;

  const ushort* Qp  = Q  + (size_t)bh * SEQ * HDIM;
  const ushort* Kp  = K  + (size_t)bh * SEQ * HDIM;
  const ushort* VTp = VT + (size_t)bh * SEQ * HDIM;  // [d][s]

  const float slope2 = exp2f(-0.5f * (float)(h + 1)) * LOG2E;
  const float c2 = 0.125f * LOG2E;

  // permuted per-element ALiBi offsets: key(kct,quad,r) =
  // (kct&1)*32 + quad*8 + (kct>>1)*4 + r
  floatx4 ab[4];
#pragma unroll
  for (int kct = 0; kct < 4; kct++)
#pragma unroll
    for (int r = 0; r < 4; r++)
      ab[kct][r] = slope2 * (float)((kct & 1) * 32 + quad * 8 + (kct >> 1) * 4 + r);
  const float q8f = (float)(quad * 8);

  // DMA staging: thread covers (row = tid>>3, pos = tid&7) and (row+32, pos).
  // LDS dest linear (elem tid*8, +2048); source chunk pre-swizzled with
  // f(row) = (row&3)|(((row>>3)&1)<<2); f(row+32)==f(row).
  const int sr0 = tid >> 3;
  const int fS  = (sr0 & 3) | (((sr0 >> 3) & 1) << 2);
  const int scc = ((tid & 7) ^ fS) * 8;               // source elem offset

  // read-side swizzles (per-lane constants):
  const int fK  = (l15 & 3) | (((l15 >> 2) & 1) << 2);  // f of K-read rows
  const int fV  = (l15 & 3) | (((l15 >> 3) & 1) << 2);  // f of V-read rows
  const int cA  = quad ^ fK;                            // K chunk (d 0..31)
  const int cV0 = quad ^ fV;                            // V chunk ks=0
  const int kRowB = (l15 >> 2) * 8 + (l15 & 3);         // K-row base

#define STAGE(KB, BUF)                                                        \
  do {                                                                        \
    gll16(&Kp[(size_t)((KB) + sr0) * HDIM + scc],       &Kl[BUF][tid * 8]);   \
    gll16(&Kp[(size_t)((KB) + sr0 + 32) * HDIM + scc],  &Kl[BUF][tid * 8 + 2048]); \
    gll16(&VTp[(size_t)sr0 * SEQ + (KB) + scc],         &Vt[BUF][tid * 8]);   \
    gll16(&VTp[(size_t)(sr0 + 32) * SEQ + (KB) + scc],  &Vt[BUF][tid * 8 + 2048]); \
  } while (0)

// one K/V tile: QK^T -> (optional mask) -> online softmax -> PV, P in regs.
// MASKED is a literal 0/1 at every expansion site.
#define ATTN_TILE(KB, CUR, MASKED)                                            \
  do {                                                                        \
    floatx4 w[4];                                                             \
    _Pragma("unroll")                                                         \
    for (int kct = 0; kct < 4; kct++) {                                       \
      const ushort* kr = &Kl[CUR][(kRowB + (kct & 1) * 32 + (kct >> 1) * 4) * 64]; \
      short8 a0 = *(const short8*)&kr[cA * 8];                                \
      short8 a1 = *(const short8*)&kr[(cA ^ 4) * 8];                          \
      floatx4 z = {};                                                         \
      z = __builtin_amdgcn_mfma_f32_16x16x32_bf16(a0, qf0, z, 0, 0, 0);       \
      z = __builtin_amdgcn_mfma_f32_16x16x32_bf16(a1, qf1, z, 0, 0, 0);       \
      w[kct] = z * c2 + ab[kct];                                              \
    }                                                                         \
    if (MASKED) {                                                             \
      const float qrel = qrowf - (float)(KB) - q8f;                           \
      _Pragma("unroll")                                                       \
      for (int kct = 0; kct < 4; kct++)                                       \
        _Pragma("unroll")                                                     \
        for (int r = 0; r < 4; r++)                                           \
          if ((float)((kct & 1) * 32 + (kct >> 1) * 4 + r) > qrel)            \
            w[kct][r] = MASK_NEG;                                             \
    }                                                                         \
    floatx4 wm4 = max4(max4(w[0], w[1]), max4(w[2], w[3]));                   \
    float mloc = fmaxf(fmaxf(wm4[0], wm4[1]), fmaxf(wm4[2], wm4[3]));         \
    mloc = fmaxf(mloc, __shfl_xor(mloc, 16, 64));                             \
    mloc = fmaxf(mloc, __shfl_xor(mloc, 32, 64));                             \
    const float bk = slope2 * (float)(KB);                                    \
    const float mlt = mloc + bk;                                              \
    const unsigned long long g = __ballot(mlt > m2 + 8.0f);                   \
    float al = 1.0f;                                                          \
    if (g) {                                                                  \
      float mn = fmaxf(m2, mlt);                                              \
      al = fast_exp2(m2 - mn);                                                \
      m2 = mn;                                                                \
    }                                                                         \
    const float mnb = m2 - bk;                                                \
    float rs = 0.f;                                                           \
    uintx4 pa0 = {}, pa1 = {};                                                \
    _Pragma("unroll")                                                         \
    for (int kct = 0; kct < 4; kct++) {                                       \
      float p0 = fast_exp2(w[kct][0] - mnb);                                  \
      float p1 = fast_exp2(w[kct][1] - mnb);                                  \
      float p2 = fast_exp2(w[kct][2] - mnb);                                  \
      float p3 = fast_exp2(w[kct][3] - mnb);                                  \
      rs += (p0 + p1) + (p2 + p3);                                            \
      if (kct & 1) {                                                          \
        pa1[(kct >> 1) * 2]     = f2bf_pk(p0, p1);                            \
        pa1[(kct >> 1) * 2 + 1] = f2bf_pk(p2, p3);                            \
      } else {                                                                \
        pa0[(kct >> 1) * 2]     = f2bf_pk(p0, p1);                            \
        pa0[(kct >> 1) * 2 + 1] = f2bf_pk(p2, p3);                            \
      }                                                                       \
    }                                                                         \
    if (g) {                                                                  \
      floatx4 alrv;                                                           \
      _Pragma("unroll")                                                       \
      for (int r = 0; r < 4; r++) alrv[r] = __shfl(al, quad * 4 + r, 16);     \
      _Pragma("unroll")                                                       \
      for (int ct = 0; ct < 4; ct++) o_acc[ct] *= alrv;                       \
      li = li * al + rs;                                                      \
    } else {                                                                  \
      li += rs;                                                               \
    }                                                                         \
    const short8 pf0 = __builtin_bit_cast(short8, pa0);                       \
    const short8 pf1 = __builtin_bit_cast(short8, pa1);                       \
    _Pragma("unroll")                                                         \
    for (int ct = 0; ct < 4; ct++) {                                          \
      const ushort* vr = &Vt[CUR][(ct * 16 + l15) * 64];                      \
      short8 vf0 = *(const short8*)&vr[cV0 * 8];                              \
      short8 vf1 = *(const short8*)&vr[(cV0 ^ 4) * 8];                        \
      o_acc[ct] = __builtin_amdgcn_mfma_f32_16x16x32_bf16(pf0, vf0, o_acc[ct], 0, 0, 0); \
      o_acc[ct] = __builtin_amdgcn_mfma_f32_16x16x32_bf16(pf1, vf1, o_acc[ct], 0, 0, 0); \
    }                                                                         \
  } while (0)

  for (int qsel = 0; qsel < 2; qsel++) {
    const int qt  = qsel ? (31 - p) : p;      // 0..31
    const int wq0 = qt * 64 + wave * 16;

    short8 qf0, qf1;
    {
      const ushort* qr = &Qp[(size_t)(wq0 + l15) * HDIM];
      qf0 = *(const short8*)&qr[quad * 8];
      qf1 = *(const short8*)&qr[32 + quad * 8];
    }

    float m2 = MASK_NEG, li = 0.f;            // li is quad-partial
    const float qrowf = (float)(wq0 + l15);
    floatx4 o_acc[4] = {};

    // prologue: barrier (prev qsel's readers of buf0), then DMA tile 0
    __syncthreads();
    STAGE(0, 0);
    __syncthreads();   // drains own vmcnt, then barrier -> buf0 ready

    const int last = qt;   // tiles 0..last; only tile `last` needs the mask
    for (int kt = 0; kt < last; kt++) {
      const int cur = kt & 1;
      STAGE((kt + 1) * 64, cur ^ 1);   // async DMA next tile
      ATTN_TILE(kt * 64, cur, 0);
      __syncthreads();                 // drain DMA + make it visible
    }

    // peeled diagonal tile (no prefetch, no trailing barrier: the next
    // qsel's pre-stage barrier covers the buffer reuse)
    ATTN_TILE(last * 64, last & 1, 1);

    // epilogue: O rows q = wq0+quad*4+r, cols d = ct*16+l15
    {
      float lif = li + __shfl_xor(li, 16, 64);
      lif += __shfl_xor(lif, 32, 64);
      float inv = 1.0f / fmaxf(lif, 1e-20f);
      float invr[4];
#pragma unroll
      for (int r = 0; r < 4; r++) invr[r] = __shfl(inv, quad * 4 + r, 16);
#pragma unroll
      for (int ct = 0; ct < 4; ct++)
#pragma unroll
        for (int r = 0; r < 4; r++) {
          int q = wq0 + quad * 4 + r;
          float v = o_acc[ct][r] * invr[r];
          Oout[(size_t)(b * SEQ + q) * EMBED + h * HDIM + ct * 16 + l15] = f2bf(v);
        }
    }
  }
#undef ATTN_TILE
#undef STAGE
}

// ---------------------------------------------------------------------------
// ws layout (bytes):
//   flag @ 0          (1024)
//   xb   @ 1024       16777216
//   WTq  @ 16778240    6291456
//   WTo  @ 23069696    2097152
//   bqb  @ 25166848       6144
//   bob  @ 25172992       2048
//   Kw   @ 25175040   16777216
//   Vw   @ 41952256   16777216   (dead after transpose_v -> reused as Aw)
//   VT   @ 58729472   16777216   -> end 75506688
//   Qw   @ 75506688 if ws fits, else Q lives in d_out.
// ---------------------------------------------------------------------------
extern "C" void kernel_launch(void* const* d_in, const int* in_sizes, int n_in,
                              void* d_out, int out_size, void* d_ws, size_t ws_size,
                              hipStream_t stream) {
  const void* x     = d_in[0];
  const void* W_qkv = d_in[2];
  const void* b_qkv = d_in[3];
  const void* W_out = d_in[4];
  const void* b_out = d_in[5];

  char* ws = (char*)d_ws;
  int*    flag = (int*)(ws + 0);
  ushort* xb   = (ushort*)(ws + 1024);
  ushort* WTq  = (ushort*)(ws + 16778240);
  ushort* WTo  = (ushort*)(ws + 23069696);
  ushort* bqb  = (ushort*)(ws + 25166848);
  ushort* bob  = (ushort*)(ws + 25172992);
  ushort* Kw   = (ushort*)(ws + 25175040);
  ushort* Vw   = (ushort*)(ws + 41952256);
  ushort* VTw  = (ushort*)(ws + 58729472);
  ushort* Aw   = Vw;   // Vw dead after transpose_v
  ushort* Qw   = (ws_size >= (size_t)75506688 + 16777216)
                   ? (ushort*)(ws + 75506688)
                   : (ushort*)d_out;   // d_out as scratch: dead until final GEMM

  detect_dtype<<<1, 256, 0, stream>>>((const uint32_t*)x, flag);

  cvt_bf16_v4<<<2048, 256, 0, stream>>>(x, xb, flag, BATCH * SEQ * EMBED / 4);
  cvt_biases<<<16, 256, 0, stream>>>(b_qkv, b_out, bqb, bob, flag);

  transpose_cvt<<<dim3(3072 / 32, 1024 / 32), 256, 0, stream>>>(W_qkv, WTq, flag, 1024, 3072);
  transpose_cvt<<<dim3(1024 / 32, 1024 / 32), 256, 0, stream>>>(W_out, WTo, flag, 1024, 1024);

  gemm128<0><<<dim3(3072 / 128, 8192 / 128), 256, 0, stream>>>(
      xb, WTq, bqb, Qw, Kw, Vw, flag, BATCH * SEQ, 3 * EMBED, EMBED);

  transpose_v<<<dim3(SEQ / 32, HDIM / 32, BATCH * NHEADS), 256, 0, stream>>>(Vw, VTw);

  attn_kernel<<<dim3(16, 16, 4), 256, 0, stream>>>(Qw, Kw, VTw, Aw);

  gemm128<1><<<dim3(1024 / 128, 8192 / 128), 256, 0, stream>>>(
      Aw, WTo, bob, (ushort*)d_out, nullptr, nullptr, flag, BATCH * SEQ, EMBED, EMBED);
}